// Round 12
// baseline (591.741 us; speedup 1.0000x reference)
//
#include <hip/hip_runtime.h>
#include <hip/hip_fp16.h>

#define NG 20000
#define NC 50000
#define NT 8000
#define EGC 600000
#define EGT 200000
#define CHUNK 25000

typedef _Float16 h8 __attribute__((ext_vector_type(8)));
typedef float f4 __attribute__((ext_vector_type(4)));

// ---------------- CSR build phase 1: LDS-privatized histograms ----------------

struct HSeg { const int* idx; int* rep; int* pos; int ne, nb, bpr, nranges, nd; };
struct HTab { HSeg s[12]; };

static __global__ __launch_bounds__(1024)
void hist_lds_kernel(HTab tab) {
    __shared__ int h[12800];
    int b = blockIdx.x, sidx = 0;
    for (;;) {
        int nbl = tab.s[sidx].nb * tab.s[sidx].nranges;
        if (b < nbl) break;
        b -= nbl; ++sidx;
    }
    const HSeg g = tab.s[sidx];
    const int row = b % g.nb, range = b / g.nb;
    const int lo = range * g.bpr;
    const int hi = min(lo + g.bpr, g.nd);
    const int nbins = hi - lo;
    for (int i = threadIdx.x; i < nbins; i += 1024) h[i] = 0;
    __syncthreads();
    const int e0 = row * CHUNK;
    const int e1 = min(e0 + CHUNK, g.ne);
    if (g.pos) {
        for (int i = e0 + (int)threadIdx.x; i < e1; i += 1024) {
            int d = g.idx[i];
            if (d >= lo && d < hi) {
                int p = atomicAdd(&h[d - lo], 1);
                g.pos[i] = p;
            }
        }
    } else {
        for (int i = e0 + (int)threadIdx.x; i < e1; i += 1024) {
            int d = g.idx[i];
            if (d >= lo && d < hi) atomicAdd(&h[d - lo], 1);
        }
    }
    __syncthreads();
    int* rp = g.rep + (size_t)row * g.nd + lo;
    for (int i = threadIdx.x; i < nbins; i += 1024) rp[i] = h[i];
}

// ---------------- scales + replica prefix ----------------

struct SPSeg { int* repd; const int* reps; float* so; float* si; int* ci_tot; int ns, nd, nb, len; };

static __device__ void sp_body(const SPSeg& s, int i) {
    if (i < s.ns) {
        int c = 0;
        for (int r = 0; r < s.nb; ++r) c += s.reps[(size_t)r * s.ns + i];
        if (c < 1) c = 1;
        s.so[i] = 1.0f / sqrtf((float)c);
    }
    if (i < s.nd) {
        int run = 0;
        for (int r = 0; r < s.nb; ++r) {
            int* p = s.repd + (size_t)r * s.nd + i;
            int t = *p; *p = run; run += t;
        }
        s.ci_tot[i] = run;
        int c = run < 1 ? 1 : run;
        s.si[i] = 1.0f / sqrtf((float)c);
    }
}

static __global__ __launch_bounds__(256)
void spscales4_kernel(SPSeg a, SPSeg b, SPSeg c, SPSeg d) {
    int i = blockIdx.x * 256 + threadIdx.x;
    if (i < a.len) { sp_body(a, i); return; }
    i -= a.len;
    if (i < b.len) { sp_body(b, i); return; }
    i -= b.len;
    if (i < c.len) { sp_body(c, i); return; }
    i -= c.len;
    if (i < d.len) { sp_body(d, i); }
}

// ---------------- fp32 -> fp16 convert with optional per-row scale fold ----------------

static __global__ __launch_bounds__(256)
void xconv_kernel(const float* __restrict__ x, const float* __restrict__ so,
                  float2* __restrict__ out, int ngran) {
    int i = blockIdx.x * 256 + threadIdx.x;
    if (i >= ngran) return;
    int row = i >> 5;
    float s = so ? so[row] : 1.0f;
    float4 v = reinterpret_cast<const float4*>(x)[i];
    float2 pk;
    *reinterpret_cast<__half2*>(&pk.x) = __floats2half2_rn(v.x * s, v.y * s);
    *reinterpret_cast<__half2*>(&pk.y) = __floats2half2_rn(v.z * s, v.w * s);
    out[i] = pk;
}

// ---------------- weight pack: fp32 W[128][128] -> fp16 MFMA B-fragments ----------------

struct PackTab { const float* w[8]; };

static __global__ __launch_bounds__(256)
void pack_kernel(PackTab pt, _Float16* __restrict__ wp) {
    int wi = blockIdx.x >> 3;
    int t = ((blockIdx.x & 7) << 8) + threadIdx.x;
    int lane = t & 63, kk = (t >> 6) & 3, ct = t >> 8;
    int g = lane >> 4, r = lane & 15;
    const float* W = pt.w[wi];
    int n = ct * 16 + r;
    int kbase = kk * 32 + g * 8;
    h8 v;
#pragma unroll
    for (int j = 0; j < 8; ++j) v[j] = (_Float16)W[(kbase + j) * 128 + n];
    *reinterpret_cast<h8*>(wp + (size_t)wi * 16384 + (size_t)t * 8) = v;
}

// ---------------- tiled block scan, VPT=8 ----------------

static __device__ void scan_body(const int* __restrict__ cnt, int* __restrict__ off, int n) {
    __shared__ int wsum[16];
    __shared__ int carry_s, total_s;
    const int t = threadIdx.x;
    const int lane = t & 63, wid = t >> 6;
    if (t == 0) carry_s = 0;
    __syncthreads();
    for (int base = 0; base < n; base += 8192) {
        int i0 = base + t * 8;
        int v[8];
        if (i0 + 8 <= n) {
            int4 a = *reinterpret_cast<const int4*>(cnt + i0);
            int4 b = *reinterpret_cast<const int4*>(cnt + i0 + 4);
            v[0]=a.x; v[1]=a.y; v[2]=a.z; v[3]=a.w; v[4]=b.x; v[5]=b.y; v[6]=b.z; v[7]=b.w;
        } else {
#pragma unroll
            for (int k = 0; k < 8; ++k) v[k] = (i0 + k < n) ? cnt[i0 + k] : 0;
        }
        int tsum = 0;
#pragma unroll
        for (int k = 0; k < 8; ++k) tsum += v[k];
        int x = tsum;
#pragma unroll
        for (int d = 1; d < 64; d <<= 1) {
            int y = __shfl_up(x, d, 64);
            if (lane >= d) x += y;
        }
        if (lane == 63) wsum[wid] = x;
        __syncthreads();
        if (wid == 0) {
            int w = (lane < 16) ? wsum[lane] : 0;
            int xx = w;
#pragma unroll
            for (int d = 1; d < 16; d <<= 1) {
                int y = __shfl_up(xx, d, 64);
                if (lane >= d) xx += y;
            }
            if (lane < 16) wsum[lane] = xx - w;
            if (lane == 15) total_s = xx;
        }
        __syncthreads();
        int run = carry_s + wsum[wid] + (x - tsum);
        if (i0 + 8 <= n) {
            int o[8];
#pragma unroll
            for (int k = 0; k < 8; ++k) { o[k] = run; run += v[k]; }
            *reinterpret_cast<int4*>(off + i0)     = make_int4(o[0], o[1], o[2], o[3]);
            *reinterpret_cast<int4*>(off + i0 + 4) = make_int4(o[4], o[5], o[6], o[7]);
        } else {
#pragma unroll
            for (int k = 0; k < 8; ++k) if (i0 + k < n) { off[i0 + k] = run; run += v[k]; }
        }
        __syncthreads();
        if (t == 0) carry_s += total_s;
        __syncthreads();
    }
    if (t == 0) off[n] = carry_s;
}

static __global__ __launch_bounds__(1024)
void scan4_kernel(const int* c0, int* o0, int n0,
                  const int* c1, int* o1, int n1,
                  const int* c2, int* o2, int n2,
                  const int* c3, int* o3, int n3) {
    if (blockIdx.x == 0) scan_body(c0, o0, n0);
    else if (blockIdx.x == 1) scan_body(c1, o1, n1);
    else if (blockIdx.x == 2) scan_body(c2, o2, n2);
    else scan_body(c3, o3, n3);
}

// ---------------- CSR build phase 2: atomic-free scatter ----------------

struct SSeg { const int* srce; const int* dste; const int* pos; const int* rep; const int* off; int* eid; int ne, nd; };

static __device__ void scatter_body(const SSeg& s, int i) {
    int row = i / CHUNK;
    int d = s.dste[i];
    s.eid[s.off[d] + s.rep[(size_t)row * s.nd + d] + s.pos[i]] = s.srce[i];
}

static __global__ __launch_bounds__(256)
void scatter4_kernel(SSeg a, SSeg b, SSeg c, SSeg d) {
    int i = blockIdx.x * 256 + threadIdx.x;
    if (i < a.ne) { scatter_body(a, i); return; }
    i -= a.ne;
    if (i < b.ne) { scatter_body(b, i); return; }
    i -= b.ne;
    if (i < c.ne) { scatter_body(c, i); return; }
    i -= c.ne;
    if (i < d.ne) { scatter_body(d, i); }
}

// ---------------- MFMA GEMM ----------------

template<int RELU, int WH>
static __global__ __launch_bounds__(256)
void gemm_mfma(const _Float16* __restrict__ X, const float* __restrict__ scale,
               const _Float16* __restrict__ Wp, const float* __restrict__ bias,
               void* __restrict__ outv, int n) {
    const int wave = threadIdx.x >> 6, lane = threadIdx.x & 63;
    const int g = lane >> 4, r = lane & 15;
    const int r0 = blockIdx.x * 64 + wave * 16;
    const int arow = r0 + r;
    h8 a[4];
    if (arow < n) {
        const _Float16* xr = X + (size_t)arow * 128;
#pragma unroll
        for (int kk = 0; kk < 4; ++kk)
            a[kk] = *reinterpret_cast<const h8*>(xr + kk * 32 + g * 8);
    } else {
#pragma unroll
        for (int kk = 0; kk < 4; ++kk)
#pragma unroll
            for (int j = 0; j < 8; ++j) a[kk][j] = (_Float16)0.f;
    }
    int orow[4]; float sc[4];
#pragma unroll
    for (int reg = 0; reg < 4; ++reg) {
        orow[reg] = r0 + g * 4 + reg;
        sc[reg] = (scale && orow[reg] < n) ? scale[orow[reg]] : 1.0f;
    }
    const h8* bp = reinterpret_cast<const h8*>(Wp);
#pragma unroll
    for (int ct = 0; ct < 8; ++ct) {
        f4 acc = {0.f, 0.f, 0.f, 0.f};
#pragma unroll
        for (int kk = 0; kk < 4; ++kk)
            acc = __builtin_amdgcn_mfma_f32_16x16x32_f16(a[kk], bp[(ct * 4 + kk) * 64 + lane], acc, 0, 0, 0);
        float bx = bias ? bias[ct * 16 + r] : 0.f;
#pragma unroll
        for (int reg = 0; reg < 4; ++reg) {
            int row = orow[reg];
            if (row < n) {
                float o = acc[reg] * sc[reg] + bx;
                if (RELU) o = fmaxf(o, 0.f);
                if (WH) reinterpret_cast<_Float16*>(outv)[(size_t)row * 128 + ct * 16 + r] = (_Float16)o;
                else    reinterpret_cast<float*>(outv)[(size_t)row * 128 + ct * 16 + r] = o;
            }
        }
    }
}

// ---------------- CSR aggregation (unsliced, small passes) ----------------
// MODE 0: out = sum(h*pre) -> fp16 (pre optional)
// MODE 2: out += relu(si*sum+b)   (fp16 RMW)

template<int MODE>
static __global__ __launch_bounds__(256)
void agg_kernel(const __half2* __restrict__ h2, const float* __restrict__ pre,
                const int* __restrict__ off, const int* __restrict__ eid,
                const float* __restrict__ si, const float* __restrict__ bias,
                const float* __restrict__ post,
                __half2* __restrict__ out, int n_dst) {
    int row = blockIdx.x * 4 + (threadIdx.x >> 6);
    if (row >= n_dst) return;
    int lane = threadIdx.x & 63;
    int e0 = off[row], e1 = off[row + 1];
    float ax = 0.f, ay = 0.f;
    int j = e0;
    for (; j + 8 <= e1; j += 8) {
        int s[8];
#pragma unroll
        for (int k = 0; k < 8; ++k) s[k] = eid[j + k];
        float2 f[8];
#pragma unroll
        for (int k = 0; k < 8; ++k) f[k] = __half22float2(h2[(size_t)s[k] * 64 + lane]);
        if (pre) {
#pragma unroll
            for (int k = 0; k < 8; ++k) { float p = pre[s[k]]; ax += f[k].x * p; ay += f[k].y * p; }
        } else {
#pragma unroll
            for (int k = 0; k < 8; ++k) { ax += f[k].x; ay += f[k].y; }
        }
    }
    for (; j < e1; ++j) {
        int s = eid[j];
        float2 f = __half22float2(h2[(size_t)s * 64 + lane]);
        float p = pre ? pre[s] : 1.0f;
        ax += f.x * p; ay += f.y * p;
    }
    __half2* o = out + (size_t)row * 64 + lane;
    if (MODE == 0) {
        *o = __floats2half2_rn(ax, ay);
    } else {
        float s = si[row];
        float2 b = reinterpret_cast<const float2*>(bias)[lane];
        float ox = fmaxf(ax * s + b.x, 0.f);
        float oy = fmaxf(ay * s + b.y, 0.f);
        if (MODE == 1 && post) { float pm = post[row]; ox *= pm; oy *= pm; }
        if (MODE == 2) { float2 cur = __half22float2(*o); ox += cur.x; oy += cur.y; }
        *o = __floats2half2_rn(ox, oy);
    }
}

// ---------------- XCD-sliced CSR aggregation (big 600k-edge passes) ----------------
// 4 column slices of 32 cols (64B); slice = blockIdx&3 so each XCD (blockIdx%8
// round-robin) touches only one slice -> per-XCD source working set /4, fits 4MB L2.
// Wave handles one dst row: 4 edge-groups x 16 lanes (half2 cols); shfl-reduce.
// MODE 0: out = sum -> fp16 ; MODE 1: out = relu(si*sum+b)*post -> fp16

template<int MODE>
static __global__ __launch_bounds__(256)
void agg_sliced(const __half2* __restrict__ h2,
                const int* __restrict__ off, const int* __restrict__ eid,
                const float* __restrict__ si, const float* __restrict__ bias,
                const float* __restrict__ post,
                __half2* __restrict__ out, int n_dst) {
    const int slice = blockIdx.x & 3;
    const int rb = blockIdx.x >> 2;
    const int row = rb * 4 + (threadIdx.x >> 6);
    if (row >= n_dst) return;
    const int lane = threadIdx.x & 63;
    const int eg = lane >> 4, c = lane & 15;
    const int colh = slice * 16 + c;          // half2 column index [0,64)
    int e0 = off[row], e1 = off[row + 1];
    float ax = 0.f, ay = 0.f;
    int j = e0;
    for (; j + 8 <= e1; j += 8) {
        int s0 = eid[j + eg], s1 = eid[j + 4 + eg];
        float2 f0 = __half22float2(h2[(size_t)s0 * 64 + colh]);
        float2 f1 = __half22float2(h2[(size_t)s1 * 64 + colh]);
        ax += f0.x + f1.x; ay += f0.y + f1.y;
    }
    for (; j < e1; j += 4) {
        int jj = j + eg;
        if (jj < e1) {
            float2 f = __half22float2(h2[(size_t)eid[jj] * 64 + colh]);
            ax += f.x; ay += f.y;
        }
    }
    ax += __shfl_xor(ax, 16, 64); ay += __shfl_xor(ay, 16, 64);
    ax += __shfl_xor(ax, 32, 64); ay += __shfl_xor(ay, 32, 64);
    if (eg == 0) {
        __half2* o = out + (size_t)row * 64 + colh;
        if (MODE == 0) {
            *o = __floats2half2_rn(ax, ay);
        } else {
            float s = si[row];
            float2 b = reinterpret_cast<const float2*>(bias)[colh];
            float ox = fmaxf(ax * s + b.x, 0.f);
            float oy = fmaxf(ay * s + b.y, 0.f);
            if (post) { float pm = post[row]; ox *= pm; oy *= pm; }
            *o = __floats2half2_rn(ox, oy);
        }
    }
}

// ---------------- orchestration ----------------

extern "C" void kernel_launch(void* const* d_in, const int* in_sizes, int n_in,
                              void* d_out, int out_size, void* d_ws, size_t ws_size,
                              hipStream_t stream) {
    const float* x_cell   = (const float*)d_in[1];
    const float* x_gotem  = (const float*)d_in[2];
    const float* W_eg_c2g = (const float*)d_in[3];  const float* b_eg_c2g = (const float*)d_in[4];
    const float* W_eg_t2g = (const float*)d_in[5];  const float* b_eg_t2g = (const float*)d_in[6];
    const float* W1_g2c   = (const float*)d_in[11]; const float* b1_g2c   = (const float*)d_in[12];
    const float* W1_g2t   = (const float*)d_in[15]; const float* b1_g2t   = (const float*)d_in[16];
    const float* W2_c2g   = (const float*)d_in[21]; const float* b2_c2g   = (const float*)d_in[22];
    const float* W2_t2g   = (const float*)d_in[25]; const float* b2_t2g   = (const float*)d_in[26];
    const float* W3_g2c   = (const float*)d_in[27]; const float* b3_g2c   = (const float*)d_in[28];
    const float* Wd_cell  = (const float*)d_in[29]; const float* bd_cell  = (const float*)d_in[30];
    const int* eg2c_src = (const int*)d_in[31]; const int* eg2c_dst = (const int*)d_in[32];
    const int* ec2g_src = (const int*)d_in[33]; const int* ec2g_dst = (const int*)d_in[34];
    const int* eg2t_src = (const int*)d_in[35]; const int* eg2t_dst = (const int*)d_in[36];
    const int* et2g_src = (const int*)d_in[37]; const int* et2g_dst = (const int*)d_in[38];

    char* p = (char*)d_ws;
    auto alloc = [&](size_t bytes) { char* r = p; p += (bytes + 255) & ~(size_t)255; return r; };
    _Float16* h16 = (_Float16*)alloc((size_t)NG * 128 * 2);
    _Float16* g16 = (_Float16*)alloc((size_t)NG * 128 * 2);
    _Float16* c16 = (_Float16*)alloc((size_t)NC * 128 * 2);
    _Float16* t16 = (_Float16*)alloc((size_t)NT * 128 * 2);
    _Float16* xch = (_Float16*)alloc((size_t)NC * 128 * 2);
    _Float16* xgh = (_Float16*)alloc((size_t)NT * 128 * 2);
    _Float16* wpk = (_Float16*)alloc((size_t)8 * 16384 * 2);
    int* off_gc = (int*)alloc((NG + 1) * 4);  int* eid_gc = (int*)alloc((size_t)EGC * 4);
    int* off_gt = (int*)alloc((NG + 1) * 4);  int* eid_gt = (int*)alloc((size_t)EGT * 4);
    int* off_c  = (int*)alloc((NC + 1) * 4);  int* eid_c  = (int*)alloc((size_t)EGC * 4);
    int* off_t  = (int*)alloc((NT + 1) * 4);  int* eid_t  = (int*)alloc((size_t)EGT * 4);
    float* so_ec2g = (float*)alloc(NC * 4);
    float* so_et2g = (float*)alloc(NT * 4);
    float* so_eg2c = (float*)alloc(NG * 4);
    float* so_eg2t = (float*)alloc(NG * 4);
    float* si_ec2g = (float*)alloc(NG * 4);
    float* si_et2g = (float*)alloc(NG * 4);
    float* si_eg2c = (float*)alloc(NC * 4);
    float* si_eg2t = (float*)alloc(NT * 4);
    int* ct_a = (int*)alloc(NG * 4);
    int* ct_b = (int*)alloc(NG * 4);
    int* ct_c = (int*)alloc(NC * 4);
    int* ct_d = (int*)alloc(NT * 4);
    int* pos_a = (int*)alloc((size_t)EGC * 4);
    int* pos_b = (int*)alloc((size_t)EGT * 4);
    int* pos_c = (int*)alloc((size_t)EGC * 4);
    int* pos_d = (int*)alloc((size_t)EGT * 4);
    int* rd_a = (int*)alloc((size_t)24 * NG * 4);
    int* rd_b = (int*)alloc((size_t)8  * NG * 4);
    int* rd_c = (int*)alloc((size_t)24 * NC * 4);
    int* rd_d = (int*)alloc((size_t)8  * NT * 4);
    int* rs_a = (int*)alloc((size_t)24 * NC * 4);
    int* rs_b = (int*)alloc((size_t)8  * NT * 4);
    int* rs_c = (int*)alloc((size_t)24 * NG * 4);
    int* rs_d = (int*)alloc((size_t)8  * NG * 4);

    auto cdiv = [](int a, int b) { return (a + b - 1) / b; };
    const int ETOT = 2 * EGC + 2 * EGT;

    // ---- weight pack ----
    PackTab pt;
    pt.w[0] = W_eg_c2g; pt.w[1] = W_eg_t2g; pt.w[2] = W1_g2c; pt.w[3] = W1_g2t;
    pt.w[4] = W2_c2g;   pt.w[5] = W2_t2g;   pt.w[6] = W3_g2c; pt.w[7] = Wd_cell;
    pack_kernel<<<64, 256, 0, stream>>>(pt, wpk);
    _Float16* Wp_egc = wpk + 0 * 16384; _Float16* Wp_egt = wpk + 1 * 16384;
    _Float16* Wp_1gc = wpk + 2 * 16384; _Float16* Wp_1gt = wpk + 3 * 16384;
    _Float16* Wp_2cg = wpk + 4 * 16384; _Float16* Wp_2tg = wpk + 5 * 16384;
    _Float16* Wp_3gc = wpk + 6 * 16384; _Float16* Wp_d   = wpk + 7 * 16384;

    // ---- phase 1: LDS histograms ----
    HTab tab;
    tab.s[0]  = {ec2g_dst, rd_a, pos_a, EGC, 24, 10000, 2, NG};
    tab.s[1]  = {et2g_dst, rd_b, pos_b, EGT,  8, 10000, 2, NG};
    tab.s[2]  = {eg2c_dst, rd_c, pos_c, EGC, 24, 12500, 4, NC};
    tab.s[3]  = {eg2t_dst, rd_d, pos_d, EGT,  8,  8000, 1, NT};
    tab.s[4]  = {ec2g_src, rs_a, nullptr, EGC, 24, 12500, 4, NC};
    tab.s[5]  = {et2g_src, rs_b, nullptr, EGT,  8,  8000, 1, NT};
    tab.s[6]  = {eg2c_src, rs_c, nullptr, EGC, 24, 10000, 2, NG};
    tab.s[7]  = {eg2t_src, rs_d, nullptr, EGT,  8, 10000, 2, NG};
    tab.s[8] = tab.s[9] = tab.s[10] = tab.s[11] = HSeg{nullptr, nullptr, nullptr, 0, 0, 1, 0, 0};
    int hist_blocks = 24*2 + 8*2 + 24*4 + 8*1 + 24*4 + 8*1 + 24*2 + 8*2;  // 336
    hist_lds_kernel<<<hist_blocks, 1024, 0, stream>>>(tab);

    // ---- scales + replica prefix ----
    SPSeg sa{rd_a, rs_a, so_ec2g, si_ec2g, ct_a, NC, NG, 24, NC};
    SPSeg sb{rd_b, rs_b, so_et2g, si_et2g, ct_b, NT, NG,  8, NG};
    SPSeg sc{rd_c, rs_c, so_eg2c, si_eg2c, ct_c, NG, NC, 24, NC};
    SPSeg sd{rd_d, rs_d, so_eg2t, si_eg2t, ct_d, NG, NT,  8, NG};
    spscales4_kernel<<<cdiv(NC + NG + NC + NG, 256), 256, 0, stream>>>(sa, sb, sc, sd);

    xconv_kernel<<<cdiv(NC * 32, 256), 256, 0, stream>>>(x_cell, so_ec2g, (float2*)xch, NC * 32);
    xconv_kernel<<<cdiv(NT * 32, 256), 256, 0, stream>>>(x_gotem, nullptr, (float2*)xgh, NT * 32);

    scan4_kernel<<<4, 1024, 0, stream>>>(ct_a, off_gc, NG, ct_b, off_gt, NG,
                                         ct_c, off_c, NC, ct_d, off_t, NT);

    // ---- phase 2: atomic-free scatter ----
    SSeg ba{ec2g_src, ec2g_dst, pos_a, rd_a, off_gc, eid_gc, EGC, NG};
    SSeg bb{et2g_src, et2g_dst, pos_b, rd_b, off_gt, eid_gt, EGT, NG};
    SSeg bc{eg2c_src, eg2c_dst, pos_c, rd_c, off_c,  eid_c,  EGC, NC};
    SSeg bd{eg2t_src, eg2t_dst, pos_d, rd_d, off_t,  eid_t,  EGT, NT};
    scatter4_kernel<<<cdiv(ETOT, 256), 256, 0, stream>>>(ba, bb, bc, bd);

    // ---- Layer E: g = relu(gconv(x_cell via ec2g) + gconv(x_gotem via et2g)) ----
    agg_sliced<0><<<cdiv(NG, 4) * 4, 256, 0, stream>>>((const __half2*)xch, off_gc, eid_gc, nullptr, nullptr, nullptr, (__half2*)h16, NG);
    gemm_mfma<1,1><<<cdiv(NG, 64), 256, 0, stream>>>(h16, si_ec2g, Wp_egc, b_eg_c2g, g16, NG);
    gemm_mfma<0,1><<<cdiv(NT, 64), 256, 0, stream>>>(xgh, so_et2g, Wp_egt, nullptr, h16, NT);
    agg_kernel<2><<<cdiv(NG, 4), 256, 0, stream>>>((const __half2*)h16, nullptr, off_gt, eid_gt, si_et2g, b_eg_t2g, nullptr, (__half2*)g16, NG);

    // ---- c1 = gconv(g via eg2c), post-scale fold so_ec2g ----
    gemm_mfma<0,1><<<cdiv(NG, 64), 256, 0, stream>>>(g16, so_eg2c, Wp_1gc, nullptr, h16, NG);
    agg_sliced<1><<<cdiv(NC, 4) * 4, 256, 0, stream>>>((const __half2*)h16, off_c, eid_c, si_eg2c, b1_g2c, so_ec2g, (__half2*)c16, NC);

    // ---- t1 = gconv(g via eg2t): agg-first ----
    agg_kernel<0><<<cdiv(NT, 4), 256, 0, stream>>>((const __half2*)g16, so_eg2t, off_t, eid_t, nullptr, nullptr, nullptr, (__half2*)h16, NT);
    gemm_mfma<1,1><<<cdiv(NT, 64), 256, 0, stream>>>(h16, si_eg2t, Wp_1gt, b1_g2t, t16, NT);

    // ---- g2 = gconv(c1 via ec2g) + gconv(t1 via et2g) ----
    agg_sliced<0><<<cdiv(NG, 4) * 4, 256, 0, stream>>>((const __half2*)c16, off_gc, eid_gc, nullptr, nullptr, nullptr, (__half2*)h16, NG);
    gemm_mfma<1,1><<<cdiv(NG, 64), 256, 0, stream>>>(h16, si_ec2g, Wp_2cg, b2_c2g, g16, NG);
    gemm_mfma<0,1><<<cdiv(NT, 64), 256, 0, stream>>>(t16, so_et2g, Wp_2tg, nullptr, h16, NT);
    agg_kernel<2><<<cdiv(NG, 4), 256, 0, stream>>>((const __half2*)h16, nullptr, off_gt, eid_gt, si_et2g, b2_t2g, nullptr, (__half2*)g16, NG);

    // ---- c3 = gconv(g2 via eg2c) ----
    gemm_mfma<0,1><<<cdiv(NG, 64), 256, 0, stream>>>(g16, so_eg2c, Wp_3gc, nullptr, h16, NG);
    agg_sliced<1><<<cdiv(NC, 4) * 4, 256, 0, stream>>>((const __half2*)h16, off_c, eid_c, si_eg2c, b3_g2c, nullptr, (__half2*)c16, NC);

    // ---- out = c3 @ Wd_cell + bd_cell (fp32 out) ----
    gemm_mfma<0,0><<<cdiv(NC, 64), 256, 0, stream>>>(c16, nullptr, Wp_d, bd_cell, d_out, NC);
}